// Round 1
// baseline (153.702 us; speedup 1.0000x reference)
//
#include <hip/hip_runtime.h>
#include <hip/hip_bf16.h>
#include <stdint.h>

#define B_   64
#define L_   4096
#define H_   128
#define T_   64
#define C_   (L_/T_)        // 64 chunks per batch row
#define BH_  (B_*H_)        // 8192
#define PADI 136            // bf16 row stride for inp tile

typedef __attribute__((ext_vector_type(8))) short short8;
typedef __attribute__((ext_vector_type(4))) short short4v;
typedef __attribute__((ext_vector_type(4))) float floatx4;
typedef __attribute__((ext_vector_type(2))) float floatx2;

#define LOG2E 1.44269504088896340736f

__device__ __forceinline__ unsigned short f2bf(float f){
    unsigned int u = __float_as_uint(f);
    u += 0x7FFFu + ((u >> 16) & 1u);      // RNE
    return (unsigned short)(u >> 16);
}
__device__ __forceinline__ float bf2f(unsigned short s){
    return __uint_as_float(((unsigned int)s) << 16);
}

// K0: W^T bf16 prep (dense [n][k]); 32 blocks.
__global__ void prep_w(const float* __restrict__ Wz, const float* __restrict__ Wh,
                       unsigned short* __restrict__ WzT, unsigned short* __restrict__ WhT){
    int b = blockIdx.x;
    const float* W = (b < 16) ? Wz : Wh;
    unsigned short* WT = (b < 16) ? WzT : WhT;
    int b16 = b & 15, tid = threadIdx.x;
    #pragma unroll
    for (int it = 0; it < 4; ++it){
        int idx = b16*1024 + it*256 + tid;    // idx = n*128 + k
        int n = idx >> 7, k = idx & 127;
        WT[idx] = f2bf(W[k*H_ + n]);
    }
}

// K2: wave-parallel Kogge-Stone scan over the 64 chunk aggregates of each
// (bb,h) row. agg2 layout [bbh][cc] (float2 A,H) -> coalesced 512B wave loads.
__global__ __launch_bounds__(256, 4)
void carry_kogge(const floatx2* __restrict__ agg2, float* __restrict__ carry_g){
    const int row  = blockIdx.x*4 + (threadIdx.x >> 6);   // 8192 rows, 4/block
    const int lane = threadIdx.x & 63;                    // lane = cc
    floatx2 v = agg2[(size_t)row*C_ + lane];
    #pragma unroll
    for (int d = 1; d < 64; d <<= 1){
        float oA = __shfl_up(v[0], d, 64);
        float oH = __shfl_up(v[1], d, 64);
        if (lane >= d){
            v[1] = fmaf(oH, v[0], v[1]);
            v[0] = oA * v[0];
        }
    }
    float eh = __shfl_up(v[1], 1, 64);
    carry_g[(size_t)row*C_ + lane] = (lane == 0) ? 0.0f : eh;
}

// ab LDS layout: row col (0..127) of 256B; 16B chunk t4 at position t4^(col&15).
// Pair (a,b) for t = t4*4+e at ushorts [chunk*8 + 2e, +1]. After the scan the
// pair holds (hw, pw) = (hloc_{t-1}*wg, P(t)*wg) in the same slots.

// Pass 1 (exact r12 best): inp + fused dual GEMM + trimmed gate epilogue +
// LDS in-place scan + coalesced pw dump + conflict-free sloc reduction.
__global__ __launch_bounds__(256, 4)
void gates_agg(const float* __restrict__ x,
               const float* __restrict__ Wp, const float* __restrict__ bp,
               const float* __restrict__ bz, const float* __restrict__ bh,
               const float* __restrict__ Wg,
               const unsigned short* __restrict__ WzT,
               const unsigned short* __restrict__ WhT,
               floatx2* __restrict__ agg2,
               float* __restrict__ sloc, unsigned short* __restrict__ pw_g)
{
    __shared__ __align__(16) unsigned short s_ab[H_*H_];    // 32 KB (inp overlays)
    __shared__ float s_bz[H_], s_bh[H_], s_wg[H_];
    __shared__ float s_part[256];
    unsigned short* inp_lds = s_ab;

    const int bid = blockIdx.x;
    const int bb  = bid / C_;
    const int cc  = bid % C_;
    const int t0g = cc * T_;
    const int tid = threadIdx.x;
    const int wv = tid >> 6, lane = tid & 63, quad = lane >> 4, l15 = lane & 15;

    if (tid < H_){ s_bz[tid] = bz[tid]; s_bh[tid] = bh[tid]; s_wg[tid] = Wg[tid]; }

    // ---- inp = x @ Wp + bp -> bf16 LDS (A layout [t][k]); Wp/bp hoisted ----
    {
        const int h0 = (tid & 15) * 8;         // iteration-invariant
        float w0[8], w1[8], w2[8], b0[8];
        #pragma unroll
        for (int m = 0; m < 8; ++m){
            w0[m] = Wp[h0+m]; w1[m] = Wp[H_+h0+m]; w2[m] = Wp[2*H_+h0+m];
            b0[m] = bp[h0+m];
        }
        #pragma unroll
        for (int it = 0; it < 4; ++it){
            int t = (tid >> 4) + it*16;
            const float* xr = x + ((size_t)bb*L_ + t0g + t)*3;
            float x0 = xr[0], x1 = xr[1], x2 = xr[2];
            short8 pk;
            #pragma unroll
            for (int m = 0; m < 8; ++m){
                float v = b0[m];
                v = fmaf(x0, w0[m], v);
                v = fmaf(x1, w1[m], v);
                v = fmaf(x2, w2[m], v);
                pk[m] = (short)f2bf(v);
            }
            *(short8*)&inp_lds[t*PADI + h0] = pk;
        }
    }
    __syncthreads();

    const int ct0 = wv*2;

    // ---- fused dual GEMM: Sz/Sh = inp @ {Wz,Wh}^T, A-frags read once ----
    floatx4 accz[4][2], acch[4][2];
    #pragma unroll
    for (int r = 0; r < 4; ++r)
        #pragma unroll
        for (int c = 0; c < 2; ++c){
            accz[r][c] = (floatx4){0.f,0.f,0.f,0.f};
            acch[r][c] = (floatx4){0.f,0.f,0.f,0.f};
        }
    #pragma unroll
    for (int kk = 0; kk < 4; ++kk){
        short8 af[4], bz_[2], bh_[2];
        #pragma unroll
        for (int r = 0; r < 4; ++r)
            af[r] = *(const short8*)&inp_lds[(r*16 + l15)*PADI + kk*32 + quad*8];
        #pragma unroll
        for (int c = 0; c < 2; ++c){
            bz_[c] = *(const short8*)&WzT[((ct0+c)*16 + l15)*H_ + kk*32 + quad*8];
            bh_[c] = *(const short8*)&WhT[((ct0+c)*16 + l15)*H_ + kk*32 + quad*8];
        }
        #pragma unroll
        for (int r = 0; r < 4; ++r)
            #pragma unroll
            for (int c = 0; c < 2; ++c){
                accz[r][c] = __builtin_amdgcn_mfma_f32_16x16x32_bf16(af[r], bz_[c], accz[r][c], 0, 0, 0);
                acch[r][c] = __builtin_amdgcn_mfma_f32_16x16x32_bf16(af[r], bh_[c], acch[r][c], 0, 0, 0);
            }
    }
    __syncthreads();   // inp reads done before ab overlay

    // ---- trimmed epilogue: a = sigmoid(-sz); b = (1-a)*tanh(sh) ----
    #pragma unroll
    for (int r = 0; r < 4; ++r){
        #pragma unroll
        for (int c = 0; c < 2; ++c){
            int col = (ct0+c)*16 + l15;
            float vbz = s_bz[col], vbh = s_bh[col];
            short8 pk;
            #pragma unroll
            for (int e = 0; e < 4; ++e){
                float szb = accz[r][c][e] + vbz;
                float a = __builtin_amdgcn_rcpf(1.0f + __builtin_amdgcn_exp2f(szb * LOG2E));
                float shb = acch[r][c][e] + vbh;
                float ex = __builtin_amdgcn_exp2f(2.0f*LOG2E*shb);
                float th = 1.0f - 2.0f*__builtin_amdgcn_rcpf(ex + 1.0f);
                float bt = (1.0f - a) * th;
                pk[2*e]   = (short)f2bf(a);
                pk[2*e+1] = (short)f2bf(bt);
            }
            int ch = (r*4 + quad) ^ l15;
            *(short8*)&s_ab[col*H_ + ch*8] = pk;
        }
    }
    __syncthreads();

    // ---- LDS-only in-place scan: (a,b) -> (hw,pw); agg out (float2) ----
    if (tid < H_){
        float A = 1.0f, h = 0.0f;
        float wgv = s_wg[tid];
        #pragma unroll
        for (int t4 = 0; t4 < 16; ++t4){
            int base = tid*H_ + ((t4 ^ (tid & 15)) << 3);
            short8 pr = *(const short8*)&s_ab[base];
            short8 wb;
            #pragma unroll
            for (int e = 0; e < 4; ++e){
                float aa = bf2f((unsigned short)pr[2*e]);
                float bv = bf2f((unsigned short)pr[2*e+1]);
                wb[2*e]   = (short)f2bf(h * wgv);   // hloc_{t-1} * wg
                wb[2*e+1] = (short)f2bf(A * wgv);   // P(t) * wg
                A *= aa;
                h = fmaf(aa, h, bv);
            }
            *(short8*)&s_ab[base] = wb;             // in-place, same banks
        }
        agg2[(size_t)(bb*H_ + tid)*C_ + cc] = (floatx2){A, h};
    }
    __syncthreads();

    // ---- coalesced pw dump: deinterleave to [col][t], all 256 threads ----
    {
        unsigned short* dst = pw_g + (size_t)bid*(T_*H_);
        #pragma unroll
        for (int i = 0; i < 8; ++i){
            int idx = i*256 + tid;                 // (col, t4)
            int col = idx >> 4, t4 = idx & 15;
            short8 pr = *(const short8*)&s_ab[col*H_ + ((t4 ^ (col & 15)) << 3)];
            short4v pw4;
            pw4[0] = pr[1]; pw4[1] = pr[3]; pw4[2] = pr[5]; pw4[3] = pr[7];
            *(short4v*)&dst[col*T_ + t4*4] = pw4;  // consecutive 8B per thread
        }
    }

    // ---- sloc reduction, conflict-free (lane index = t) ----
    {
        int t = tid & 63, w4 = tid >> 6;
        int t4 = t >> 2, e2 = (t & 3)*2;
        float s = 0.0f;
        #pragma unroll
        for (int j = 0; j < 32; ++j){
            int col = w4*32 + j;
            s += bf2f(s_ab[col*H_ + ((t4 ^ (col & 15)) << 3) + e2]);
        }
        s_part[w4*64 + t] = s;
    }
    __syncthreads();
    if (tid < 64)
        sloc[(size_t)bid*T_ + tid] =
            s_part[tid] + s_part[64+tid] + s_part[128+tid] + s_part[192+tid];
}

// Pass 2: XCD-aligned chunk grouping. gates_agg block bb*64+cc lands on XCD
// cc%8 (round-robin dispatch), so chunk cc's pw tile is hot in that XCD's L2.
// Group chunks {c4, c4+16, c4+32, c4+48} (all == c4 mod 16): this block
// (bid = bb*16+c4 -> XCD c4%8) reads only pw written by its own XCD.
__global__ __launch_bounds__(256, 4)
void apply2(const unsigned short* __restrict__ pw_g,
            const float* __restrict__ carry_g,
            const float* __restrict__ sloc, const float* __restrict__ bg,
            float* __restrict__ preds)
{
    __shared__ float s_c[4][H_];
    __shared__ float s_part[4][256];
    const int bid = blockIdx.x;          // 1024 blocks
    const int bb  = bid >> 4;
    const int c4  = bid & 15;            // chunk k = c4 + 16*k
    const int tid = threadIdx.x;
    const int wv = tid >> 6, lane = tid & 63;
    const int cl = lane >> 3, t8 = lane & 7;

    // stage 4 carry vectors (strided chunks)
    #pragma unroll
    for (int i = 0; i < 2; ++i){
        int idx = tid + i*256;           // (h, k)
        int k = idx & 3, h = idx >> 2;
        s_c[k][h] = carry_g[(size_t)(bb*H_ + h)*C_ + c4 + 16*k];
    }
    __syncthreads();

    #pragma unroll
    for (int k = 0; k < 4; ++k){
        const int chunk = c4 + 16*k;
        const unsigned short* src = pw_g + (size_t)(bb*C_ + chunk)*(T_*H_);
        float s8[8];
        #pragma unroll
        for (int e = 0; e < 8; ++e) s8[e] = 0.0f;
        #pragma unroll
        for (int g = 0; g < 4; ++g){
            int col = wv*32 + g*8 + cl;
            short8 pw8 = *(const short8*)&src[col*T_ + t8*8];
            float cv = s_c[k][col];
            #pragma unroll
            for (int e = 0; e < 8; ++e)
                s8[e] = fmaf(cv, bf2f((unsigned short)pw8[e]), s8[e]);
        }
        #pragma unroll
        for (int d = 8; d < 64; d <<= 1)
            #pragma unroll
            for (int e = 0; e < 8; ++e)
                s8[e] += __shfl_xor(s8[e], d, 64);
        if (lane < 8){
            #pragma unroll
            for (int e = 0; e < 8; ++e)
                s_part[k][wv*64 + t8*8 + e] = s8[e];
        }
    }
    __syncthreads();

    {
        int k = tid >> 6, t = tid & 63;
        float s = s_part[k][t] + s_part[k][64+t] + s_part[k][128+t] + s_part[k][192+t];
        int chunk = c4 + 16*k;
        preds[(size_t)bb*L_ + chunk*T_ + t] =
            s + sloc[(size_t)(bb*C_ + chunk)*T_ + t] + bg[0];
    }
}

extern "C" void kernel_launch(void* const* d_in, const int* in_sizes, int n_in,
                              void* d_out, int out_size, void* d_ws, size_t ws_size,
                              hipStream_t stream){
    const float* x  = (const float*)d_in[0];
    const float* Wp = (const float*)d_in[1];
    const float* bp = (const float*)d_in[2];
    const float* Wz = (const float*)d_in[3];
    const float* bz = (const float*)d_in[4];
    const float* Wh = (const float*)d_in[5];
    const float* bh = (const float*)d_in[6];
    const float* Wg = (const float*)d_in[7];
    const float* bg = (const float*)d_in[8];
    float* preds = (float*)d_out;

    uint8_t* w8 = (uint8_t*)d_ws;
    unsigned short* WzT = (unsigned short*)(w8);
    unsigned short* WhT = (unsigned short*)(w8 + 32768);
    floatx2* agg2 = (floatx2*)(w8 + 65536);                   // 4 MB [bbh][cc]
    float* sloc   = (float*)(w8 + 65536 + 8u*BH_*C_);         // 1 MB
    float* carry  = (float*)(w8 + 65536 + 12u*BH_*C_);        // 2 MB [bbh][cc]
    unsigned short* pw_g = (unsigned short*)(w8 + 65536 + 16u*BH_*C_);  // 64 MB

    hipLaunchKernelGGL(prep_w, dim3(32), dim3(256), 0, stream, Wz, Wh, WzT, WhT);
    hipLaunchKernelGGL(gates_agg, dim3(B_*C_), dim3(256), 0, stream,
                       x, Wp, bp, bz, bh, Wg, WzT, WhT, agg2, sloc, pw_g);
    hipLaunchKernelGGL(carry_kogge, dim3(BH_/4), dim3(256), 0, stream, agg2, carry);
    hipLaunchKernelGGL(apply2, dim3(B_*C_/4), dim3(256), 0, stream,
                       pw_g, carry, sloc, bg, preds);
}

// Round 2
// 152.958 us; speedup vs baseline: 1.0049x; 1.0049x over previous
//
#include <hip/hip_runtime.h>
#include <hip/hip_bf16.h>
#include <stdint.h>

#define B_   64
#define L_   4096
#define H_   128
#define HG_  32            // h-channels per block
#define NG_  4             // h-groups
#define TI_  256           // timesteps per iteration
#define NIT_ 16            // iterations (L/TI)
#define PADI 136           // bf16 row stride for inp tile

typedef __attribute__((ext_vector_type(8))) short short8;
typedef __attribute__((ext_vector_type(4))) short short4v;
typedef __attribute__((ext_vector_type(4))) float floatx4;
typedef __attribute__((ext_vector_type(2))) float floatx2;

#define LOG2E 1.44269504088896340736f

__device__ __forceinline__ unsigned short f2bf(float f){
    unsigned int u = __float_as_uint(f);
    u += 0x7FFFu + ((u >> 16) & 1u);      // RNE
    return (unsigned short)(u >> 16);
}
__device__ __forceinline__ float bf2f(unsigned short s){
    return __uint_as_float(((unsigned int)s) << 16);
}

// K0: W^T bf16 prep (dense [n][k]); 32 blocks. (unchanged, proven)
__global__ void prep_w(const float* __restrict__ Wz, const float* __restrict__ Wh,
                       unsigned short* __restrict__ WzT, unsigned short* __restrict__ WhT){
    int b = blockIdx.x;
    const float* W = (b < 16) ? Wz : Wh;
    unsigned short* WT = (b < 16) ? WzT : WhT;
    int b16 = b & 15, tid = threadIdx.x;
    #pragma unroll
    for (int it = 0; it < 4; ++it){
        int idx = b16*1024 + it*256 + tid;    // idx = n*128 + k
        int n = idx >> 7, k = idx & 127;
        WT[idx] = f2bf(W[k*H_ + n]);
    }
}

// Fused full-timeline kernel. 256 blocks x 1024 threads, 1 block/CU.
// Block (bb, g): batch row bb, h-channels [g*32, g*32+32).
// Carry h_run is register-resident across the 16 sequential 256-t iterations:
// no chunk-aggregate pass, no carry pass, no 128MB pw round-trip.
// LDS swizzle: value (t, col) stored at [t][col ^ (t&31)] -> conflict-free
// reads when col spans lanes (scan) and 2-way when t spans lanes (reduce).
__global__ __launch_bounds__(1024, 4)
void fused_rnn(const float* __restrict__ x,
               const float* __restrict__ Wp, const float* __restrict__ bp,
               const float* __restrict__ bz, const float* __restrict__ bh,
               const float* __restrict__ Wg,
               const unsigned short* __restrict__ WzT,
               const unsigned short* __restrict__ WhT,
               float* __restrict__ partials)
{
    __shared__ __align__(16) unsigned short s_inp[TI_*PADI];  // 69632 B
    __shared__ __align__(16) unsigned int  s_ab[TI_*HG_];     // 32768 B ((a,th) u32; reused as f32 y)
    __shared__ __align__(16) floatx2 s_agg[32*32];            // 8192 B seg aggregates
    __shared__ float s_hh[32*32];                             // 4096 B seg-entry h values

    const int bid = blockIdx.x;
    const int bb  = bid >> 2;
    const int g   = bid & 3;
    const int tid = threadIdx.x;
    const int wv = tid >> 6, lane = tid & 63, quad = lane >> 4, l15 = lane & 15;

    // --- roles ---
    const int G   = wv >> 3;          // 0: z-gate wave, 1: h-gate wave
    const int tt0 = wv & 7;           // handles t-tiles tt0 and tt0+8
    const int sh  = tid & 31;         // C1/C3: h index
    const int ss  = tid >> 5;         // C1/C3: seg index (8 t each)
    const int rh  = tid >> 5;         // C2: h index (remapped: segs in-lane)
    const int rs  = tid & 31;         // C2: seg index
    const int cg  = tid & 31;         // inp: col group (4 cols)
    const int tg  = tid >> 5;         // inp: t group (8 t)
    const int rt  = tid >> 2;         // reduce: t
    const int rp  = tid & 3;          // reduce: part (8 h each)

    // --- one-time register preloads ---
    const unsigned short* WT = G ? WhT : WzT;
    short8 bfr[2][4];
    #pragma unroll
    for (int ct = 0; ct < 2; ++ct)
        #pragma unroll
        for (int kk = 0; kk < 4; ++kk)
            bfr[ct][kk] = *(const short8*)&WT[(g*HG_ + ct*16 + l15)*H_ + kk*32 + quad*8];
    float biasv[2];
    #pragma unroll
    for (int ct = 0; ct < 2; ++ct)
        biasv[ct] = (G ? bh : bz)[g*HG_ + ct*16 + l15];
    const float wgv = Wg[g*HG_ + sh];
    float w0[4], w1[4], w2[4], bc[4];
    #pragma unroll
    for (int m = 0; m < 4; ++m){
        w0[m] = Wp[cg*4+m]; w1[m] = Wp[H_+cg*4+m]; w2[m] = Wp[2*H_+cg*4+m];
        bc[m] = bp[cg*4+m];
    }
    float h_run = 0.0f;               // carry: consistent across each 32-lane group (per rh)

    for (int it = 0; it < NIT_; ++it){
        // ---- phase A: reduce prev iter's y (in s_ab as f32) + write inp tile ----
        if (it > 0){
            float s = 0.0f;
            #pragma unroll
            for (int i = 0; i < 8; ++i){
                int col = rp*8 + i;
                s += ((const float*)s_ab)[rt*HG_ + (col ^ (rt & 31))];
            }
            s += __shfl_xor(s, 1);
            s += __shfl_xor(s, 2);
            if (rp == 0)
                partials[(((size_t)(g*B_ + bb)) << 12) + (it-1)*TI_ + rt] = s;
        }
        {
            const float* xr0 = x + ((size_t)bb*L_ + it*TI_ + tg*8)*3;
            #pragma unroll
            for (int j = 0; j < 8; ++j){
                int t = tg*8 + j;
                float x0 = xr0[j*3], x1 = xr0[j*3+1], x2 = xr0[j*3+2];
                short4v pk;
                #pragma unroll
                for (int m = 0; m < 4; ++m){
                    float v = bc[m];
                    v = fmaf(x0, w0[m], v);
                    v = fmaf(x1, w1[m], v);
                    v = fmaf(x2, w2[m], v);
                    pk[m] = (short)f2bf(v);
                }
                *(short4v*)&s_inp[t*PADI + cg*4] = pk;
            }
        }
        __syncthreads();

        // ---- phase B: MFMA (one gate per wave, 2 t-tiles) + epilogue -> s_ab b16 ----
        #pragma unroll
        for (int tl = 0; tl < 2; ++tl){
            int tile = tt0 + tl*8;
            floatx4 acc0 = (floatx4){0.f,0.f,0.f,0.f};
            floatx4 acc1 = (floatx4){0.f,0.f,0.f,0.f};
            #pragma unroll
            for (int kk = 0; kk < 4; ++kk){
                short8 af = *(const short8*)&s_inp[(tile*16 + l15)*PADI + kk*32 + quad*8];
                acc0 = __builtin_amdgcn_mfma_f32_16x16x32_bf16(af, bfr[0][kk], acc0, 0, 0, 0);
                acc1 = __builtin_amdgcn_mfma_f32_16x16x32_bf16(af, bfr[1][kk], acc1, 0, 0, 0);
            }
            #pragma unroll
            for (int ct = 0; ct < 2; ++ct){
                floatx4 acc = ct ? acc1 : acc0;
                int hl = ct*16 + l15;
                #pragma unroll
                for (int e = 0; e < 4; ++e){
                    int t = tile*16 + quad*4 + e;
                    float v = acc[e] + biasv[ct];
                    float r;
                    if (G == 0){
                        r = __builtin_amdgcn_rcpf(1.0f + __builtin_amdgcn_exp2f(v * LOG2E)); // a = 1-z
                    } else {
                        float ex = __builtin_amdgcn_exp2f(2.0f*LOG2E*v);
                        r = 1.0f - 2.0f*__builtin_amdgcn_rcpf(ex + 1.0f);                    // tanh
                    }
                    ((unsigned short*)s_ab)[(t*HG_ + (hl ^ (t & 31)))*2 + G] = f2bf(r);
                }
            }
        }
        __syncthreads();

        // ---- phase C1: per-seg local scan (8 t), keep a/b in regs, aggregate out ----
        float aj[8], bj[8];
        {
            float A = 1.0f, Q = 0.0f;
            #pragma unroll
            for (int j = 0; j < 8; ++j){
                int t = ss*8 + j;
                unsigned int u = s_ab[t*HG_ + (sh ^ (t & 31))];
                float a  = bf2f((unsigned short)(u & 0xffffu));
                float th = bf2f((unsigned short)(u >> 16));
                float b  = fmaf(-a, th, th);          // (1-a)*th
                aj[j] = a; bj[j] = b;
                Q = fmaf(a, Q, b);
                A *= a;
            }
            s_agg[ss*32 + (sh ^ ss)] = (floatx2){A, Q};
        }
        __syncthreads();

        // ---- phase C2: Kogge-Stone over 32 segs (remapped: segs in-lane) ----
        {
            floatx2 v = s_agg[rs*32 + (rh ^ rs)];
            float P = v[0], Hq = v[1];
            #pragma unroll
            for (int d = 1; d < 32; d <<= 1){
                float pP = __shfl_up(P, d, 32);
                float pH = __shfl_up(Hq, d, 32);
                if (rs >= d){
                    Hq = fmaf(P, pH, Hq);
                    P  = P * pP;
                }
            }
            float eP = __shfl_up(P, 1, 32);
            float eH = __shfl_up(Hq, 1, 32);
            if (rs == 0){ eP = 1.0f; eH = 0.0f; }
            float tP = __shfl(P, 31, 32);
            float tH = __shfl(Hq, 31, 32);
            s_hh[rs*32 + (rh ^ rs)] = fmaf(eP, h_run, eH);   // h at seg entry - 1
            h_run = fmaf(tP, h_run, tH);                     // carry to next iter
        }
        __syncthreads();

        // ---- phase C3: replay serial 8 steps, emit y = wg * h_{t-1} into s_ab (f32) ----
        {
            float hh = s_hh[ss*32 + (sh ^ ss)];
            #pragma unroll
            for (int j = 0; j < 8; ++j){
                int t = ss*8 + j;
                ((float*)s_ab)[t*HG_ + (sh ^ (t & 31))] = wgv * hh;
                hh = fmaf(aj[j], hh, bj[j]);
            }
        }
        __syncthreads();
    }

    // ---- final reduce for the last iteration ----
    {
        float s = 0.0f;
        #pragma unroll
        for (int i = 0; i < 8; ++i){
            int col = rp*8 + i;
            s += ((const float*)s_ab)[rt*HG_ + (col ^ (rt & 31))];
        }
        s += __shfl_xor(s, 1);
        s += __shfl_xor(s, 2);
        if (rp == 0)
            partials[(((size_t)(g*B_ + bb)) << 12) + (NIT_-1)*TI_ + rt] = s;
    }
}

// Gather: preds = bg + sum of 4 group partials. 256 blocks x 1024.
__global__ __launch_bounds__(1024)
void gather(const float* __restrict__ partials, const float* __restrict__ bg,
            float* __restrict__ preds)
{
    size_t idx = (size_t)blockIdx.x*1024 + threadIdx.x;     // 0 .. 262143
    const size_t GSTRIDE = (size_t)B_ * L_;                 // 262144
    float s = bg[0];
    s += partials[idx];
    s += partials[GSTRIDE + idx];
    s += partials[2*GSTRIDE + idx];
    s += partials[3*GSTRIDE + idx];
    preds[idx] = s;
}

extern "C" void kernel_launch(void* const* d_in, const int* in_sizes, int n_in,
                              void* d_out, int out_size, void* d_ws, size_t ws_size,
                              hipStream_t stream){
    const float* x  = (const float*)d_in[0];
    const float* Wp = (const float*)d_in[1];
    const float* bp = (const float*)d_in[2];
    const float* Wz = (const float*)d_in[3];
    const float* bz = (const float*)d_in[4];
    const float* Wh = (const float*)d_in[5];
    const float* bh = (const float*)d_in[6];
    const float* Wg = (const float*)d_in[7];
    const float* bg = (const float*)d_in[8];
    float* preds = (float*)d_out;

    uint8_t* w8 = (uint8_t*)d_ws;
    unsigned short* WzT = (unsigned short*)(w8);
    unsigned short* WhT = (unsigned short*)(w8 + 32768);
    float* partials = (float*)(w8 + 65536);                 // 4 MB: [g][bb][t] f32

    hipLaunchKernelGGL(prep_w, dim3(32), dim3(256), 0, stream, Wz, Wh, WzT, WhT);
    hipLaunchKernelGGL(fused_rnn, dim3(B_*NG_), dim3(1024), 0, stream,
                       x, Wp, bp, bz, bh, Wg, WzT, WhT, partials);
    hipLaunchKernelGGL(gather, dim3(B_*L_/1024), dim3(1024), 0, stream,
                       partials, bg, preds);
}